// Round 23
// baseline (677.386 us; speedup 1.0000x reference)
//
#include <hip/hip_runtime.h>
#include <hip/hip_bf16.h>

using bf16 = __hip_bfloat16;
typedef __attribute__((ext_vector_type(8))) short short8;   // 8 bf16 = 4 VGPRs
typedef __attribute__((ext_vector_type(4))) float f32x4;    // MFMA C/D frag

#define MFMA_BF16(A,B,C) __builtin_amdgcn_mfma_f32_16x16x32_bf16((A),(B),(C),0,0,0)

static __device__ __forceinline__ unsigned bf16bits(float f) {
  union { bf16 h; unsigned short u; } cv; cv.h = __float2bfloat16(f); return cv.u;
}

// async global->LDS, 16B per lane. LDS dest = wave-uniform base + lane*16.
static __device__ __forceinline__ void gload16(const void* g, void* l) {
  __builtin_amdgcn_global_load_lds(
      (const __attribute__((address_space(1))) void*)g,
      (__attribute__((address_space(3))) void*)l, 16, 0, 0);
}

// ---------------------------------------------------------------------------
// Generic bf16 GEMM: C[M,N] = A[M,K] @ B[N,K]^T (+bias)
// m97 structure: 128x128 tile, BK=32, 4 waves (2x2), 4x4 16x16x32 frags/wave.
// EPI 1: tanh(x*BN_SCALE) -> bf16 (predictor).  EPI 2: g0p scatter.
// ---------------------------------------------------------------------------
template<int EPI>
__global__ __launch_bounds__(256)
void gemm_bt(const bf16* __restrict__ A, const bf16* __restrict__ B,
             const float* __restrict__ bias1, const float* __restrict__ bias2,
             float* __restrict__ Cf, bf16* __restrict__ Cb,
             int M, int N, int K, int Nreal)
{
  __shared__ __align__(1024) bf16 As[128*32];
  __shared__ __align__(1024) bf16 Bs[128*32];
  const int tid  = threadIdx.x;
  const int wave = tid >> 6, lane = tid & 63;
  const int wr = wave >> 1, wc = wave & 1;
  const int row0 = blockIdx.y * 128;
  const int col0 = blockIdx.x * 128;

  f32x4 acc[4][4];
  #pragma unroll
  for (int m = 0; m < 4; ++m)
    #pragma unroll
    for (int n = 0; n < 4; ++n) { f32x4 z = {0.f,0.f,0.f,0.f}; acc[m][n] = z; }

  const int r_sub = lane >> 2;   // 0..15 (row within 16-row stage group)
  const int kc    = lane & 3;    // 16B chunk within 64B row

  for (int k0 = 0; k0 < K; k0 += 32) {
    __syncthreads();
    #pragma unroll
    for (int j = 0; j < 2; ++j) {
      const int rb = wave*32 + j*16;
      gload16(A + (size_t)(row0 + rb + r_sub)*K + k0 + kc*8,
              (void*)((char*)As + (size_t)rb*64));
      gload16(B + (size_t)(col0 + rb + r_sub)*K + k0 + kc*8,
              (void*)((char*)Bs + (size_t)rb*64));
    }
    __syncthreads();

    short8 af[4], bfv[4];
    #pragma unroll
    for (int m = 0; m < 4; ++m)
      af[m] = *(const short8*)(As + (wr*64 + m*16 + (lane&15))*32 + (lane>>4)*8);
    #pragma unroll
    for (int n = 0; n < 4; ++n)
      bfv[n] = *(const short8*)(Bs + (wc*64 + n*16 + (lane&15))*32 + (lane>>4)*8);
    #pragma unroll
    for (int m = 0; m < 4; ++m)
      #pragma unroll
      for (int n = 0; n < 4; ++n)
        acc[m][n] = MFMA_BF16(af[m], bfv[n], acc[m][n]);
  }

  const float BN_SCALE = 0.9999950000374997f;  // 1/sqrt(1+1e-5)
  #pragma unroll
  for (int m = 0; m < 4; ++m) {
    const int rg0 = row0 + wr*64 + m*16 + ((lane>>4)<<2);
    #pragma unroll
    for (int n = 0; n < 4; ++n) {
      const int cg = col0 + wc*64 + n*16 + (lane&15);
      if (EPI == 2) {
        const int bq = cg >> 4, q = cg & 15;
        const int orig = (q>>2)*1024 + bq*4 + (q&3);   // permuted -> original col
        const float bb = bias1[orig] + bias2[orig];
        #pragma unroll
        for (int j = 0; j < 4; ++j) {
          const int row = rg0 + j;
          Cf[((size_t)bq*64 + (row>>5))*512 + (size_t)(row&31)*16 + q]
              = acc[m][n][j] + bb;
        }
      } else if (cg < Nreal) {
        float bb = 0.f;
        if (bias1) bb += bias1[cg];
        if (bias2) bb += bias2[cg];
        #pragma unroll
        for (int j = 0; j < 4; ++j) {
          float v = acc[m][n][j] + bb;
          v = tanhf(v * BN_SCALE);
          Cb[(size_t)(rg0+j)*Nreal + cg] = __float2bfloat16(v);
        }
      }
    }
  }
}

// ---------------------------------------------------------------------------
// Decoder GEMM v3 (rounds 15-17): 256x256 tile, 512 threads, double-buffered
// counted-vmcnt staging, non-temporal C stores (helps the 410MB stream).
// ---------------------------------------------------------------------------
__global__ __launch_bounds__(512, 2)
void gemm_dec(const bf16* __restrict__ A, const bf16* __restrict__ B,
              const float* __restrict__ bias, float* __restrict__ C,
              int M, int N, int K, int Nreal)
{
  __shared__ __align__(1024) bf16 As[2*256*32];   // 32KB: [slot][row][32]
  __shared__ __align__(1024) bf16 Bs[2*256*32];
  const int tid  = threadIdx.x;
  const int wave = tid >> 6, lane = tid & 63;
  const int wr = wave >> 2, wc = wave & 3;   // 2 x 4 wave grid
  const int row0 = blockIdx.y * 256;
  const int col0 = blockIdx.x * 256;

  f32x4 acc[8][4];
  #pragma unroll
  for (int m = 0; m < 8; ++m)
    #pragma unroll
    for (int n = 0; n < 4; ++n) { f32x4 z = {0.f,0.f,0.f,0.f}; acc[m][n] = z; }

  const int r_sub = lane >> 2;   // row within 16-row stage group
  const int kc    = lane & 3;    // 16B chunk within 64B row

  auto STAGE = [&](int sl, int k0) {
    #pragma unroll
    for (int j = 0; j < 2; ++j) {
      const int rb = wave*32 + j*16;           // 8 waves x 32 rows = 256
      gload16(A + (size_t)(row0 + rb + r_sub)*K + k0 + kc*8,
              (void*)((char*)As + (size_t)sl*16384 + (size_t)rb*64));
      gload16(B + (size_t)(col0 + rb + r_sub)*K + k0 + kc*8,
              (void*)((char*)Bs + (size_t)sl*16384 + (size_t)rb*64));
    }
  };

  const int NT = K >> 5;                     // 16 for K=512
  STAGE(0, 0);
  if (NT > 1) STAGE(1, 32);

  for (int kk = 0; kk < NT; ++kk) {
    const int cur = kk & 1;
    if (kk == NT - 1) asm volatile("s_waitcnt vmcnt(0)" ::: "memory");
    else              asm volatile("s_waitcnt vmcnt(4)" ::: "memory");
    __builtin_amdgcn_sched_barrier(0);
    __builtin_amdgcn_s_barrier();            // all waves' stage-kk landed

    const bf16* Ab = As + (size_t)cur*8192;
    const bf16* Bb = Bs + (size_t)cur*8192;
    short8 af[8], bfv[4];
    #pragma unroll
    for (int m = 0; m < 8; ++m)
      af[m] = *(const short8*)(Ab + (wr*128 + m*16 + (lane&15))*32 + (lane>>4)*8);
    #pragma unroll
    for (int n = 0; n < 4; ++n)
      bfv[n] = *(const short8*)(Bb + (wc*64 + n*16 + (lane&15))*32 + (lane>>4)*8);
    #pragma unroll
    for (int m = 0; m < 8; ++m)
      #pragma unroll
      for (int n = 0; n < 4; ++n)
        acc[m][n] = MFMA_BF16(af[m], bfv[n], acc[m][n]);

    asm volatile("s_waitcnt lgkmcnt(0)" ::: "memory");   // reads of buf done
    __builtin_amdgcn_sched_barrier(0);                   // rule #18
    __builtin_amdgcn_s_barrier();            // all waves done reading buf cur
    if (kk + 2 < NT) STAGE(cur, (kk + 2) * 32);
  }

  #pragma unroll
  for (int m = 0; m < 8; ++m) {
    const int rg0 = row0 + wr*128 + m*16 + ((lane>>4)<<2);
    #pragma unroll
    for (int n = 0; n < 4; ++n) {
      const int cg = col0 + wc*64 + n*16 + (lane&15);
      if (cg < Nreal) {
        const float bb = bias[cg];
        #pragma unroll
        for (int j = 0; j < 4; ++j)
          __builtin_nontemporal_store(acc[m][n][j] + bb,
                                      C + (size_t)(rg0+j)*Nreal + cg);
      }
    }
  }
}

// ---------------------------------------------------------------------------
// Persistent LSTM recurrence — proven sync structure. Fusions:
// (a) prologue reg-stages weights directly from fp32 into LDS;
// (b) Wd/Wp cast, T14 async-split: waves 1-3 ISSUE the 3 f32x4 loads at the
//     TOP of step s (latency hides under the MFMA+gate phase; drains at #1
//     where h loads already dominate), hold in regs, then convert+STORE
//     after the flag publish (stores drain at the NEXT step's #2). Wave 0
//     does no cast work (its poll vmcnt stays clean — round 22, -7us).
//     Round 22 issued loads post-publish: their cold-HBM latency hit
//     barrier #3's drain (+46us). Cached (nt regressed WRITE 2x, round 21).
// ---------------------------------------------------------------------------
__global__ __launch_bounds__(256, 1)
void k_lstm_persist(const bf16* __restrict__ hinit, const float* __restrict__ cx,
                    const float* __restrict__ Whh0, const float* __restrict__ Wih1,
                    const float* __restrict__ Whh1, const float* __restrict__ g0p,
                    const float* __restrict__ bih1, const float* __restrict__ bhh1,
                    const float* __restrict__ Wd, const float* __restrict__ Wp,
                    bf16* __restrict__ Wdb, bf16* __restrict__ Wpb,
                    bf16* __restrict__ h0_all, bf16* __restrict__ h1_all,
                    float* __restrict__ tail, unsigned* __restrict__ flags)
{
  const int b    = blockIdx.x;
  const int tid  = threadIdx.x;
  const int wave = tid >> 6, lane = tid & 63;

  __shared__ __align__(1024) bf16 Wlds[96*512];   // 96 KB: [chunk][lane][8]
  __shared__ float P[4][2][32][20];               // partial sums (padded)

  // (a) one-time: reg-stage + cast this block's weights into LDS
  #pragma unroll
  for (int it = 0; it < 24; ++it) {
    const int idx = it*256 + tid;
    const int chunkp = idx >> 6;            // 0..95
    const int l = idx & 63;
    const int p = chunkp >> 5, c = chunkp & 31;
    const float* W = (p == 0) ? Whh0 : (p == 1 ? Wih1 : Whh1);
    const int j = l & 15;
    const int row = (j>>2)*1024 + b*4 + (j&3);
    const int k = c*32 + (l>>4)*8;
    const float* src = W + (size_t)row*1024 + k;
    const float4 v0 = *(const float4*)(src);
    const float4 v1 = *(const float4*)(src + 4);
    short8 pk;
    pk[0] = (short)bf16bits(v0.x); pk[1] = (short)bf16bits(v0.y);
    pk[2] = (short)bf16bits(v0.z); pk[3] = (short)bf16bits(v0.w);
    pk[4] = (short)bf16bits(v1.x); pk[5] = (short)bf16bits(v1.y);
    pk[6] = (short)bf16bits(v1.z); pk[7] = (short)bf16bits(v1.w);
    *(short8*)(Wlds + ((size_t)chunkp*64 + l)*8) = pk;
  }

  // gate/cell phase mapping: one LSTM cell per thread
  const int layer = tid >> 7;
  const int cell  = tid & 127;
  const int r     = cell >> 2;
  const int hc    = cell & 3;
  const int col   = b*4 + hc;
  float creg = cx[(size_t)layer*32768 + (size_t)r*1024 + col];
  float bsum[4];
  #pragma unroll
  for (int g = 0; g < 4; ++g)
    bsum[g] = (layer == 1) ? (bih1[g*1024 + col] + bhh1[g*1024 + col]) : 0.f;

  const int arow = lane & 15;
  const int koff = (lane >> 4) * 8;

  // per-lane poll pointers (wave 0 only uses them)
  const unsigned* fp0 = flags + (lane*4+0)*32;
  const unsigned* fp1 = flags + (lane*4+1)*32;
  const unsigned* fp2 = flags + (lane*4+2)*32;
  const unsigned* fp3 = flags + (lane*4+3)*32;

  __syncthreads();   // weights staged (LDS writes visible block-wide)

  for (int s = 0; s < 65; ++s) {
    const bf16* hA = (s == 0) ? hinit           : h0_all + (size_t)(s-1)*32768;
    const bf16* hB = (s <= 1) ? (hinit + 32768) : h1_all + (size_t)(s-2)*32768;

    // (b-load) cast slice loads ISSUED FIRST (waves 1-3, s<64): latency
    // hides under h loads + MFMA + gate; drains at #1 with everything else.
    f32x4 cv[3];
    long cbase = 0;
    if (wave != 0 && s < 64) {
      cbase = (((long)s*256 + b)*192 + (tid - 64))*3;
      #pragma unroll
      for (int uu = 0; uu < 3; ++uu) {
        const long u = cbase + uu;
        f32x4 zz = {0.f,0.f,0.f,0.f};
        cv[uu] = zz;
        if (u < 6422528) {                   // Wd-pad: 50176*512/4 units
          const long e = u*4;
          const int row = (int)(e >> 9);
          if (row < 50000) cv[uu] = *(const f32x4*)(Wd + e);
        } else if (u < 6553600) {            // Wp: 512*1024/4 units
          cv[uu] = *(const f32x4*)(Wp + (u - 6422528)*4);
        }
      }
    }

    // normal cached h loads (L2 broadcast); all issued up front
    short8 a0[8], a1[8], c0[8], c1[8];
    #pragma unroll
    for (int i = 0; i < 8; ++i) {
      const int kb = wave*256 + i*32 + koff;
      a0[i] = *(const short8*)(hA + (size_t)arow*1024      + kb);
      a1[i] = *(const short8*)(hA + (size_t)(arow+16)*1024 + kb);
      c0[i] = *(const short8*)(hB + (size_t)arow*1024      + kb);
      c1[i] = *(const short8*)(hB + (size_t)(arow+16)*1024 + kb);
    }
    float gpre[4] = {0.f, 0.f, 0.f, 0.f};
    if (layer == 0 && s < 64) {
      const float* gr = g0p + ((size_t)(b*64 + s)*32 + r)*16;
      #pragma unroll
      for (int g = 0; g < 4; ++g) gpre[g] = gr[g*4 + hc];
    }

    f32x4 z = {0.f,0.f,0.f,0.f};
    f32x4 acc00 = z, acc01 = z, acc10 = z, acc11 = z;
    #pragma unroll
    for (int i = 0; i < 8; ++i) {
      const int ks = wave*8 + i;
      short8 w0 = *(const short8*)(Wlds + ((size_t)(     ks)*64 + lane)*8);
      short8 w1 = *(const short8*)(Wlds + ((size_t)(32 + ks)*64 + lane)*8);
      short8 w2 = *(const short8*)(Wlds + ((size_t)(64 + ks)*64 + lane)*8);
      acc00 = MFMA_BF16(a0[i], w0, acc00);   // layer0: Whh0 @ h0[s-1]
      acc01 = MFMA_BF16(a1[i], w0, acc01);
      acc10 = MFMA_BF16(a0[i], w1, acc10);   // layer1: Wih1 @ h0[s-1]
      acc11 = MFMA_BF16(a1[i], w1, acc11);
      acc10 = MFMA_BF16(c0[i], w2, acc10);   // layer1 += Whh1 @ h1[s-2]
      acc11 = MFMA_BF16(c1[i], w2, acc11);
    }

    #pragma unroll
    for (int j = 0; j < 4; ++j) {
      const int pr = (lane >> 4)*4 + j;
      P[wave][0][pr     ][lane & 15] = acc00[j];
      P[wave][0][pr + 16][lane & 15] = acc01[j];
      P[wave][1][pr     ][lane & 15] = acc10[j];
      P[wave][1][pr + 16][lane & 15] = acc11[j];
    }
    __syncthreads();                         // #1: P complete

    const int t = s - layer;
    if (t >= 0 && t < 64) {
      float v[4];
      #pragma unroll
      for (int g = 0; g < 4; ++g) {
        const int j = g*4 + hc;
        v[g] = P[0][layer][r][j] + P[1][layer][r][j]
             + P[2][layer][r][j] + P[3][layer][r][j] + bsum[g] + gpre[g];
      }
      const float iv = 1.f/(1.f + expf(-v[0]));
      const float fv = 1.f/(1.f + expf(-v[1]));
      const float gv = tanhf(v[2]);
      const float ov = 1.f/(1.f + expf(-v[3]));
      creg = fv*creg + iv*gv;
      const float hn = ov*tanhf(creg);
      // gather 4 cells -> one 8B agent-relaxed store straight to LLC
      unsigned hu  = bf16bits(hn);
      unsigned p01 = hu | ((unsigned)__shfl_xor((int)hu, 1) << 16);
      unsigned p23 = (unsigned)__shfl_xor((int)p01, 2);
      if (hc == 0) {
        bf16* hp = (layer ? h1_all : h0_all) + (size_t)t*32768 + (size_t)r*1024 + b*4;
        unsigned long long v64 = (unsigned long long)p01
                               | ((unsigned long long)p23 << 32);
        __hip_atomic_store((unsigned long long*)hp, v64,
                           __ATOMIC_RELAXED, __HIP_MEMORY_SCOPE_AGENT);
      }
      if (t == 63) {
        tail[(size_t)layer*32768 + (size_t)r*1024 + col]         = hn;
        tail[65536 + (size_t)layer*32768 + (size_t)r*1024 + col] = creg;
      }
    }
    if (s == 64) break;

    __syncthreads();                         // #2: drain h publishes (vmcnt 0)
    if (tid == 0) {
      // RELAXED publish straight to LLC (sc1), pinned by asm volatile:
      // no buffer_wbl2, no compiler reordering.
      asm volatile("global_store_dword %0, %1, off sc0 sc1\n\t"
                   "s_waitcnt vmcnt(0)"
                   :: "v"(flags + b*32), "v"((unsigned)(s + 1)) : "memory");
    }

    // (b-store) convert + store the pre-loaded cast slice (waves 1-3).
    // Stores drain at the NEXT step's #2 — off the critical path.
    if (wave != 0) {
      #pragma unroll
      for (int uu = 0; uu < 3; ++uu) {
        const long u = cbase + uu;
        uint2 pkd;
        pkd.x = bf16bits(cv[uu][0]) | (bf16bits(cv[uu][1]) << 16);
        pkd.y = bf16bits(cv[uu][2]) | (bf16bits(cv[uu][3]) << 16);
        if (u < 6422528) {
          *(uint2*)(Wdb + u*4) = pkd;
        } else if (u < 6553600) {
          *(uint2*)(Wpb + (u - 6422528)*4) = pkd;
        }
      }
    }

    if (wave == 0) {                         // only wave 0 polls (clean vmcnt)
      const unsigned su = (unsigned)s;
      for (;;) {
        unsigned v0, v1, v2, v3;
        asm volatile("global_load_dword %0, %1, off sc0 sc1" : "=v"(v0) : "v"(fp0));
        asm volatile("global_load_dword %0, %1, off sc0 sc1" : "=v"(v1) : "v"(fp1));
        asm volatile("global_load_dword %0, %1, off sc0 sc1" : "=v"(v2) : "v"(fp2));
        asm volatile("global_load_dword %0, %1, off sc0 sc1" : "=v"(v3) : "v"(fp3));
        asm volatile("s_waitcnt vmcnt(0)" ::: "memory");
        bool ok = (v0 > su) & (v1 > su) & (v2 > su) & (v3 > su);
        if (__all(ok)) break;
        __builtin_amdgcn_s_sleep(1);
      }
    }
    __syncthreads();                         // #3: release all waves
    asm volatile("" ::: "memory");           // no hoisting of h loads above
    __builtin_amdgcn_sched_barrier(0);
  }
}

// ---------------------------------------------------------------------------
// small helpers
// ---------------------------------------------------------------------------
// Wih0 cast with ROW PERMUTATION: dst row n <- src row ((n>>2)&3)*1024 + (n>>4)*4 + (n&3)
__global__ void k_cvt_perm(const float* __restrict__ src, bf16* __restrict__ dst) {
  const int n = blockIdx.x;                 // 0..4095 (permuted row)
  const int orig = ((n>>2)&3)*1024 + (n>>4)*4 + (n&3);
  const float4 v = ((const float4*)(src + (size_t)orig*512))[threadIdx.x];
  bf16* d = dst + (size_t)n*512 + threadIdx.x*4;
  d[0] = __float2bfloat16(v.x); d[1] = __float2bfloat16(v.y);
  d[2] = __float2bfloat16(v.z); d[3] = __float2bfloat16(v.w);
}

__global__ void k_init(const float* __restrict__ hx, bf16* __restrict__ hinit,
                       unsigned* __restrict__ flags) {
  int i = blockIdx.x*blockDim.x + threadIdx.x;
  if (i < 8192) flags[i] = 0u;
  if (i < 65536) hinit[i] = __float2bfloat16(hx[i]);
}

__global__ void k_embed(const int* __restrict__ ids, const float* __restrict__ emb_w,
                        bf16* __restrict__ out) {
  const int row = blockIdx.x;
  const int tok = ids[row];
  const float4 v = ((const float4*)(emb_w + (size_t)tok*512))[threadIdx.x];
  bf16* d = out + (size_t)row*512 + threadIdx.x*4;
  d[0] = __float2bfloat16(v.x); d[1] = __float2bfloat16(v.y);
  d[2] = __float2bfloat16(v.z); d[3] = __float2bfloat16(v.w);
}

// ---------------------------------------------------------------------------
extern "C" void kernel_launch(void* const* d_in, const int* in_sizes, int n_in,
                              void* d_out, int out_size, void* d_ws, size_t ws_size,
                              hipStream_t stream) {
  const int*   ids  = (const int*)d_in[0];
  const float* hx   = (const float*)d_in[1];
  const float* cx   = (const float*)d_in[2];
  const float* embw = (const float*)d_in[3];
  const float* Wih0 = (const float*)d_in[4];
  const float* Whh0 = (const float*)d_in[5];
  const float* bih0 = (const float*)d_in[6];
  const float* bhh0 = (const float*)d_in[7];
  const float* Wih1 = (const float*)d_in[8];
  const float* Whh1 = (const float*)d_in[9];
  const float* bih1 = (const float*)d_in[10];
  const float* bhh1 = (const float*)d_in[11];
  const float* Wp   = (const float*)d_in[12];
  const float* bp   = (const float*)d_in[13];
  const float* Wd   = (const float*)d_in[14];
  const float* bd   = (const float*)d_in[15];
  float* out = (float*)d_out;

  char* w = (char*)d_ws;
  bf16* Wih0b = (bf16*)w; w += 4096l*512*2;       // permuted rows
  bf16* Wpb   = (bf16*)w; w += 512l*1024*2;
  bf16* Wdb   = (bf16*)w; w += 50176l*512*2;      // padded to 196*256 rows
  bf16* embb  = (bf16*)w; w += 2048l*512*2;
  float* g0p  = (float*)w; w += 2048l*4096*4;     // [b][t][r][q] layout
  bf16* h0a   = (bf16*)w; w += 2048l*1024*2;
  bf16* h1a   = (bf16*)w; w += 2048l*1024*2;
  bf16* hinit = (bf16*)w; w += 2l*32*1024*2;
  bf16* pb    = (bf16*)w; w += 2048l*512*2;
  unsigned* flags = (unsigned*)w; w += 8192*4;

  k_cvt_perm<<<4096, 128, 0, stream>>>(Wih0, Wih0b);
  k_init<<<256, 256, 0, stream>>>(hx, hinit, flags);
  k_embed<<<2048, 128, 0, stream>>>(ids, embw, embb);

  // layer-0 input-side GEMM for ALL timesteps -> g0p layout; folds bih0+bhh0
  gemm_bt<2><<<dim3(32, 16), 256, 0, stream>>>(
      embb, Wih0b, bih0, bhh0, g0p, nullptr, 2048, 4096, 512, 4096);

  // persistent pipelined recurrence: one dispatch, 65 super-steps.
  // Wd/Wp casts: loads at step top (hidden under compute), stores after
  // publish (drain at next step's #2). Wave 0 exempt.
  float* tail = out + 102400000l;
  k_lstm_persist<<<256, 256, 0, stream>>>(hinit, cx, Whh0, Wih1, Whh1, g0p,
                                          bih1, bhh1, Wd, Wp, Wdb, Wpb,
                                          h0a, h1a, tail, flags);

  // predictor: Linear + BN(eval) + tanh -> bf16
  gemm_bt<1><<<dim3(4, 16), 256, 0, stream>>>(
      h1a, Wpb, bp, nullptr, nullptr, pb, 2048, 512, 1024, 512);

  // decoder: [2048,512] @ [50176,512]^T (padded), 256x256 tiles, double-
  // buffered counted-vmcnt staging, non-temporal C stores
  gemm_dec<<<dim3(196, 8), 512, 0, stream>>>(
      pb, Wdb, bd, out, 2048, 50176, 512, 50000);
}

// Round 24
// 667.696 us; speedup vs baseline: 1.0145x; 1.0145x over previous
//
#include <hip/hip_runtime.h>
#include <hip/hip_bf16.h>

using bf16 = __hip_bfloat16;
typedef __attribute__((ext_vector_type(8))) short short8;   // 8 bf16 = 4 VGPRs
typedef __attribute__((ext_vector_type(4))) float f32x4;    // MFMA C/D frag

#define MFMA_BF16(A,B,C) __builtin_amdgcn_mfma_f32_16x16x32_bf16((A),(B),(C),0,0,0)

static __device__ __forceinline__ unsigned bf16bits(float f) {
  union { bf16 h; unsigned short u; } cv; cv.h = __float2bfloat16(f); return cv.u;
}

// async global->LDS, 16B per lane. LDS dest = wave-uniform base + lane*16.
static __device__ __forceinline__ void gload16(const void* g, void* l) {
  __builtin_amdgcn_global_load_lds(
      (const __attribute__((address_space(1))) void*)g,
      (__attribute__((address_space(3))) void*)l, 16, 0, 0);
}

// ---------------------------------------------------------------------------
// Generic bf16 GEMM: C[M,N] = A[M,K] @ B[N,K]^T (+bias)
// m97 structure: 128x128 tile, BK=32, 4 waves (2x2), 4x4 16x16x32 frags/wave.
// EPI 1: tanh(x*BN_SCALE) -> bf16 (predictor).  EPI 2: g0p scatter.
// ---------------------------------------------------------------------------
template<int EPI>
__global__ __launch_bounds__(256)
void gemm_bt(const bf16* __restrict__ A, const bf16* __restrict__ B,
             const float* __restrict__ bias1, const float* __restrict__ bias2,
             float* __restrict__ Cf, bf16* __restrict__ Cb,
             int M, int N, int K, int Nreal)
{
  __shared__ __align__(1024) bf16 As[128*32];
  __shared__ __align__(1024) bf16 Bs[128*32];
  const int tid  = threadIdx.x;
  const int wave = tid >> 6, lane = tid & 63;
  const int wr = wave >> 1, wc = wave & 1;
  const int row0 = blockIdx.y * 128;
  const int col0 = blockIdx.x * 128;

  f32x4 acc[4][4];
  #pragma unroll
  for (int m = 0; m < 4; ++m)
    #pragma unroll
    for (int n = 0; n < 4; ++n) { f32x4 z = {0.f,0.f,0.f,0.f}; acc[m][n] = z; }

  const int r_sub = lane >> 2;   // 0..15 (row within 16-row stage group)
  const int kc    = lane & 3;    // 16B chunk within 64B row

  for (int k0 = 0; k0 < K; k0 += 32) {
    __syncthreads();
    #pragma unroll
    for (int j = 0; j < 2; ++j) {
      const int rb = wave*32 + j*16;
      gload16(A + (size_t)(row0 + rb + r_sub)*K + k0 + kc*8,
              (void*)((char*)As + (size_t)rb*64));
      gload16(B + (size_t)(col0 + rb + r_sub)*K + k0 + kc*8,
              (void*)((char*)Bs + (size_t)rb*64));
    }
    __syncthreads();

    short8 af[4], bfv[4];
    #pragma unroll
    for (int m = 0; m < 4; ++m)
      af[m] = *(const short8*)(As + (wr*64 + m*16 + (lane&15))*32 + (lane>>4)*8);
    #pragma unroll
    for (int n = 0; n < 4; ++n)
      bfv[n] = *(const short8*)(Bs + (wc*64 + n*16 + (lane&15))*32 + (lane>>4)*8);
    #pragma unroll
    for (int m = 0; m < 4; ++m)
      #pragma unroll
      for (int n = 0; n < 4; ++n)
        acc[m][n] = MFMA_BF16(af[m], bfv[n], acc[m][n]);
  }

  const float BN_SCALE = 0.9999950000374997f;  // 1/sqrt(1+1e-5)
  #pragma unroll
  for (int m = 0; m < 4; ++m) {
    const int rg0 = row0 + wr*64 + m*16 + ((lane>>4)<<2);
    #pragma unroll
    for (int n = 0; n < 4; ++n) {
      const int cg = col0 + wc*64 + n*16 + (lane&15);
      if (EPI == 2) {
        const int bq = cg >> 4, q = cg & 15;
        const int orig = (q>>2)*1024 + bq*4 + (q&3);   // permuted -> original col
        const float bb = bias1[orig] + bias2[orig];
        #pragma unroll
        for (int j = 0; j < 4; ++j) {
          const int row = rg0 + j;
          Cf[((size_t)bq*64 + (row>>5))*512 + (size_t)(row&31)*16 + q]
              = acc[m][n][j] + bb;
        }
      } else if (cg < Nreal) {
        float bb = 0.f;
        if (bias1) bb += bias1[cg];
        if (bias2) bb += bias2[cg];
        #pragma unroll
        for (int j = 0; j < 4; ++j) {
          float v = acc[m][n][j] + bb;
          v = tanhf(v * BN_SCALE);
          Cb[(size_t)(rg0+j)*Nreal + cg] = __float2bfloat16(v);
        }
      }
    }
  }
}

// ---------------------------------------------------------------------------
// Decoder GEMM v3 (rounds 15-17): 256x256 tile, 512 threads, double-buffered
// counted-vmcnt staging, non-temporal C stores (helps the 410MB stream).
// ---------------------------------------------------------------------------
__global__ __launch_bounds__(512, 2)
void gemm_dec(const bf16* __restrict__ A, const bf16* __restrict__ B,
              const float* __restrict__ bias, float* __restrict__ C,
              int M, int N, int K, int Nreal)
{
  __shared__ __align__(1024) bf16 As[2*256*32];   // 32KB: [slot][row][32]
  __shared__ __align__(1024) bf16 Bs[2*256*32];
  const int tid  = threadIdx.x;
  const int wave = tid >> 6, lane = tid & 63;
  const int wr = wave >> 2, wc = wave & 3;   // 2 x 4 wave grid
  const int row0 = blockIdx.y * 256;
  const int col0 = blockIdx.x * 256;

  f32x4 acc[8][4];
  #pragma unroll
  for (int m = 0; m < 8; ++m)
    #pragma unroll
    for (int n = 0; n < 4; ++n) { f32x4 z = {0.f,0.f,0.f,0.f}; acc[m][n] = z; }

  const int r_sub = lane >> 2;   // row within 16-row stage group
  const int kc    = lane & 3;    // 16B chunk within 64B row

  auto STAGE = [&](int sl, int k0) {
    #pragma unroll
    for (int j = 0; j < 2; ++j) {
      const int rb = wave*32 + j*16;           // 8 waves x 32 rows = 256
      gload16(A + (size_t)(row0 + rb + r_sub)*K + k0 + kc*8,
              (void*)((char*)As + (size_t)sl*16384 + (size_t)rb*64));
      gload16(B + (size_t)(col0 + rb + r_sub)*K + k0 + kc*8,
              (void*)((char*)Bs + (size_t)sl*16384 + (size_t)rb*64));
    }
  };

  const int NT = K >> 5;                     // 16 for K=512
  STAGE(0, 0);
  if (NT > 1) STAGE(1, 32);

  for (int kk = 0; kk < NT; ++kk) {
    const int cur = kk & 1;
    if (kk == NT - 1) asm volatile("s_waitcnt vmcnt(0)" ::: "memory");
    else              asm volatile("s_waitcnt vmcnt(4)" ::: "memory");
    __builtin_amdgcn_sched_barrier(0);
    __builtin_amdgcn_s_barrier();            // all waves' stage-kk landed

    const bf16* Ab = As + (size_t)cur*8192;
    const bf16* Bb = Bs + (size_t)cur*8192;
    short8 af[8], bfv[4];
    #pragma unroll
    for (int m = 0; m < 8; ++m)
      af[m] = *(const short8*)(Ab + (wr*128 + m*16 + (lane&15))*32 + (lane>>4)*8);
    #pragma unroll
    for (int n = 0; n < 4; ++n)
      bfv[n] = *(const short8*)(Bb + (wc*64 + n*16 + (lane&15))*32 + (lane>>4)*8);
    #pragma unroll
    for (int m = 0; m < 8; ++m)
      #pragma unroll
      for (int n = 0; n < 4; ++n)
        acc[m][n] = MFMA_BF16(af[m], bfv[n], acc[m][n]);

    asm volatile("s_waitcnt lgkmcnt(0)" ::: "memory");   // reads of buf done
    __builtin_amdgcn_sched_barrier(0);                   // rule #18
    __builtin_amdgcn_s_barrier();            // all waves done reading buf cur
    if (kk + 2 < NT) STAGE(cur, (kk + 2) * 32);
  }

  #pragma unroll
  for (int m = 0; m < 8; ++m) {
    const int rg0 = row0 + wr*128 + m*16 + ((lane>>4)<<2);
    #pragma unroll
    for (int n = 0; n < 4; ++n) {
      const int cg = col0 + wc*64 + n*16 + (lane&15);
      if (cg < Nreal) {
        const float bb = bias[cg];
        #pragma unroll
        for (int j = 0; j < 4; ++j)
          __builtin_nontemporal_store(acc[m][n][j] + bb,
                                      C + (size_t)(rg0+j)*Nreal + cg);
      }
    }
  }
}

// ---------------------------------------------------------------------------
// Persistent LSTM recurrence — round-22 proven optimum (668us total).
// (a) prologue reg-stages weights directly from fp32 into LDS;
// (b) Wd/Wp cast: CACHED loads/stores, WAVES 1-3 ONLY, post-publish.
//     (T14 pre-issue regressed +23us: MFMA phase too short to hide HBM
//     latency and it delayed barrier #1's h-load drain. nt regressed
//     WRITE 2x. Wave-0 exemption keeps its poll vmcnt clean: -7us.)
// ---------------------------------------------------------------------------
__global__ __launch_bounds__(256, 1)
void k_lstm_persist(const bf16* __restrict__ hinit, const float* __restrict__ cx,
                    const float* __restrict__ Whh0, const float* __restrict__ Wih1,
                    const float* __restrict__ Whh1, const float* __restrict__ g0p,
                    const float* __restrict__ bih1, const float* __restrict__ bhh1,
                    const float* __restrict__ Wd, const float* __restrict__ Wp,
                    bf16* __restrict__ Wdb, bf16* __restrict__ Wpb,
                    bf16* __restrict__ h0_all, bf16* __restrict__ h1_all,
                    float* __restrict__ tail, unsigned* __restrict__ flags)
{
  const int b    = blockIdx.x;
  const int tid  = threadIdx.x;
  const int wave = tid >> 6, lane = tid & 63;

  __shared__ __align__(1024) bf16 Wlds[96*512];   // 96 KB: [chunk][lane][8]
  __shared__ float P[4][2][32][20];               // partial sums (padded)

  // (a) one-time: reg-stage + cast this block's weights into LDS
  #pragma unroll
  for (int it = 0; it < 24; ++it) {
    const int idx = it*256 + tid;
    const int chunkp = idx >> 6;            // 0..95
    const int l = idx & 63;
    const int p = chunkp >> 5, c = chunkp & 31;
    const float* W = (p == 0) ? Whh0 : (p == 1 ? Wih1 : Whh1);
    const int j = l & 15;
    const int row = (j>>2)*1024 + b*4 + (j&3);
    const int k = c*32 + (l>>4)*8;
    const float* src = W + (size_t)row*1024 + k;
    const float4 v0 = *(const float4*)(src);
    const float4 v1 = *(const float4*)(src + 4);
    short8 pk;
    pk[0] = (short)bf16bits(v0.x); pk[1] = (short)bf16bits(v0.y);
    pk[2] = (short)bf16bits(v0.z); pk[3] = (short)bf16bits(v0.w);
    pk[4] = (short)bf16bits(v1.x); pk[5] = (short)bf16bits(v1.y);
    pk[6] = (short)bf16bits(v1.z); pk[7] = (short)bf16bits(v1.w);
    *(short8*)(Wlds + ((size_t)chunkp*64 + l)*8) = pk;
  }

  // gate/cell phase mapping: one LSTM cell per thread
  const int layer = tid >> 7;
  const int cell  = tid & 127;
  const int r     = cell >> 2;
  const int hc    = cell & 3;
  const int col   = b*4 + hc;
  float creg = cx[(size_t)layer*32768 + (size_t)r*1024 + col];
  float bsum[4];
  #pragma unroll
  for (int g = 0; g < 4; ++g)
    bsum[g] = (layer == 1) ? (bih1[g*1024 + col] + bhh1[g*1024 + col]) : 0.f;

  const int arow = lane & 15;
  const int koff = (lane >> 4) * 8;

  // per-lane poll pointers (wave 0 only uses them)
  const unsigned* fp0 = flags + (lane*4+0)*32;
  const unsigned* fp1 = flags + (lane*4+1)*32;
  const unsigned* fp2 = flags + (lane*4+2)*32;
  const unsigned* fp3 = flags + (lane*4+3)*32;

  __syncthreads();   // weights staged (LDS writes visible block-wide)

  for (int s = 0; s < 65; ++s) {
    const bf16* hA = (s == 0) ? hinit           : h0_all + (size_t)(s-1)*32768;
    const bf16* hB = (s <= 1) ? (hinit + 32768) : h1_all + (size_t)(s-2)*32768;

    // normal cached h loads (L2 broadcast); all issued up front
    short8 a0[8], a1[8], c0[8], c1[8];
    #pragma unroll
    for (int i = 0; i < 8; ++i) {
      const int kb = wave*256 + i*32 + koff;
      a0[i] = *(const short8*)(hA + (size_t)arow*1024      + kb);
      a1[i] = *(const short8*)(hA + (size_t)(arow+16)*1024 + kb);
      c0[i] = *(const short8*)(hB + (size_t)arow*1024      + kb);
      c1[i] = *(const short8*)(hB + (size_t)(arow+16)*1024 + kb);
    }
    float gpre[4] = {0.f, 0.f, 0.f, 0.f};
    if (layer == 0 && s < 64) {
      const float* gr = g0p + ((size_t)(b*64 + s)*32 + r)*16;
      #pragma unroll
      for (int g = 0; g < 4; ++g) gpre[g] = gr[g*4 + hc];
    }

    f32x4 z = {0.f,0.f,0.f,0.f};
    f32x4 acc00 = z, acc01 = z, acc10 = z, acc11 = z;
    #pragma unroll
    for (int i = 0; i < 8; ++i) {
      const int ks = wave*8 + i;
      short8 w0 = *(const short8*)(Wlds + ((size_t)(     ks)*64 + lane)*8);
      short8 w1 = *(const short8*)(Wlds + ((size_t)(32 + ks)*64 + lane)*8);
      short8 w2 = *(const short8*)(Wlds + ((size_t)(64 + ks)*64 + lane)*8);
      acc00 = MFMA_BF16(a0[i], w0, acc00);   // layer0: Whh0 @ h0[s-1]
      acc01 = MFMA_BF16(a1[i], w0, acc01);
      acc10 = MFMA_BF16(a0[i], w1, acc10);   // layer1: Wih1 @ h0[s-1]
      acc11 = MFMA_BF16(a1[i], w1, acc11);
      acc10 = MFMA_BF16(c0[i], w2, acc10);   // layer1 += Whh1 @ h1[s-2]
      acc11 = MFMA_BF16(c1[i], w2, acc11);
    }

    #pragma unroll
    for (int j = 0; j < 4; ++j) {
      const int pr = (lane >> 4)*4 + j;
      P[wave][0][pr     ][lane & 15] = acc00[j];
      P[wave][0][pr + 16][lane & 15] = acc01[j];
      P[wave][1][pr     ][lane & 15] = acc10[j];
      P[wave][1][pr + 16][lane & 15] = acc11[j];
    }
    __syncthreads();                         // #1: P complete

    const int t = s - layer;
    if (t >= 0 && t < 64) {
      float v[4];
      #pragma unroll
      for (int g = 0; g < 4; ++g) {
        const int j = g*4 + hc;
        v[g] = P[0][layer][r][j] + P[1][layer][r][j]
             + P[2][layer][r][j] + P[3][layer][r][j] + bsum[g] + gpre[g];
      }
      const float iv = 1.f/(1.f + expf(-v[0]));
      const float fv = 1.f/(1.f + expf(-v[1]));
      const float gv = tanhf(v[2]);
      const float ov = 1.f/(1.f + expf(-v[3]));
      creg = fv*creg + iv*gv;
      const float hn = ov*tanhf(creg);
      // gather 4 cells -> one 8B agent-relaxed store straight to LLC
      unsigned hu  = bf16bits(hn);
      unsigned p01 = hu | ((unsigned)__shfl_xor((int)hu, 1) << 16);
      unsigned p23 = (unsigned)__shfl_xor((int)p01, 2);
      if (hc == 0) {
        bf16* hp = (layer ? h1_all : h0_all) + (size_t)t*32768 + (size_t)r*1024 + b*4;
        unsigned long long v64 = (unsigned long long)p01
                               | ((unsigned long long)p23 << 32);
        __hip_atomic_store((unsigned long long*)hp, v64,
                           __ATOMIC_RELAXED, __HIP_MEMORY_SCOPE_AGENT);
      }
      if (t == 63) {
        tail[(size_t)layer*32768 + (size_t)r*1024 + col]         = hn;
        tail[65536 + (size_t)layer*32768 + (size_t)r*1024 + col] = creg;
      }
    }
    if (s == 64) break;

    __syncthreads();                         // #2: drain h publishes (vmcnt 0)
    if (tid == 0) {
      // RELAXED publish straight to LLC (sc1), pinned by asm volatile:
      // no buffer_wbl2, no compiler reordering.
      asm volatile("global_store_dword %0, %1, off sc0 sc1\n\t"
                   "s_waitcnt vmcnt(0)"
                   :: "v"(flags + b*32), "v"((unsigned)(s + 1)) : "memory");
    }

    // (b) hidden weight-cast slice, WAVES 1-3 only, CACHED loads/stores.
    if (wave != 0) {
      const long base = (((long)s*256 + b)*192 + (tid - 64))*3;
      #pragma unroll
      for (int uu = 0; uu < 3; ++uu) {
        const long u = base + uu;
        if (u < 6422528) {                   // Wd-pad: 50176*512/4 units
          const long e = u*4;
          const int row = (int)(e >> 9);
          float4 v = (row < 50000) ? *(const float4*)(Wd + e)
                                   : make_float4(0.f,0.f,0.f,0.f);
          unsigned lo = bf16bits(v.x) | (bf16bits(v.y) << 16);
          unsigned hi = bf16bits(v.z) | (bf16bits(v.w) << 16);
          uint2 pkd; pkd.x = lo; pkd.y = hi;
          *(uint2*)(Wdb + e) = pkd;
        } else if (u < 6553600) {            // Wp: 512*1024/4 units
          const long e = (u - 6422528)*4;
          float4 v = *(const float4*)(Wp + e);
          unsigned lo = bf16bits(v.x) | (bf16bits(v.y) << 16);
          unsigned hi = bf16bits(v.z) | (bf16bits(v.w) << 16);
          uint2 pkd; pkd.x = lo; pkd.y = hi;
          *(uint2*)(Wpb + e) = pkd;
        }
      }
    }

    if (wave == 0) {                         // only wave 0 polls (clean vmcnt)
      const unsigned su = (unsigned)s;
      for (;;) {
        unsigned v0, v1, v2, v3;
        asm volatile("global_load_dword %0, %1, off sc0 sc1" : "=v"(v0) : "v"(fp0));
        asm volatile("global_load_dword %0, %1, off sc0 sc1" : "=v"(v1) : "v"(fp1));
        asm volatile("global_load_dword %0, %1, off sc0 sc1" : "=v"(v2) : "v"(fp2));
        asm volatile("global_load_dword %0, %1, off sc0 sc1" : "=v"(v3) : "v"(fp3));
        asm volatile("s_waitcnt vmcnt(0)" ::: "memory");
        bool ok = (v0 > su) & (v1 > su) & (v2 > su) & (v3 > su);
        if (__all(ok)) break;
        __builtin_amdgcn_s_sleep(1);
      }
    }
    __syncthreads();                         // #3: release all waves
    asm volatile("" ::: "memory");           // no hoisting of h loads above
    __builtin_amdgcn_sched_barrier(0);
  }
}

// ---------------------------------------------------------------------------
// small helpers
// ---------------------------------------------------------------------------
// Wih0 cast with ROW PERMUTATION: dst row n <- src row ((n>>2)&3)*1024 + (n>>4)*4 + (n&3)
__global__ void k_cvt_perm(const float* __restrict__ src, bf16* __restrict__ dst) {
  const int n = blockIdx.x;                 // 0..4095 (permuted row)
  const int orig = ((n>>2)&3)*1024 + (n>>4)*4 + (n&3);
  const float4 v = ((const float4*)(src + (size_t)orig*512))[threadIdx.x];
  bf16* d = dst + (size_t)n*512 + threadIdx.x*4;
  d[0] = __float2bfloat16(v.x); d[1] = __float2bfloat16(v.y);
  d[2] = __float2bfloat16(v.z); d[3] = __float2bfloat16(v.w);
}

__global__ void k_init(const float* __restrict__ hx, bf16* __restrict__ hinit,
                       unsigned* __restrict__ flags) {
  int i = blockIdx.x*blockDim.x + threadIdx.x;
  if (i < 8192) flags[i] = 0u;
  if (i < 65536) hinit[i] = __float2bfloat16(hx[i]);
}

__global__ void k_embed(const int* __restrict__ ids, const float* __restrict__ emb_w,
                        bf16* __restrict__ out) {
  const int row = blockIdx.x;
  const int tok = ids[row];
  const float4 v = ((const float4*)(emb_w + (size_t)tok*512))[threadIdx.x];
  bf16* d = out + (size_t)row*512 + threadIdx.x*4;
  d[0] = __float2bfloat16(v.x); d[1] = __float2bfloat16(v.y);
  d[2] = __float2bfloat16(v.z); d[3] = __float2bfloat16(v.w);
}

// ---------------------------------------------------------------------------
extern "C" void kernel_launch(void* const* d_in, const int* in_sizes, int n_in,
                              void* d_out, int out_size, void* d_ws, size_t ws_size,
                              hipStream_t stream) {
  const int*   ids  = (const int*)d_in[0];
  const float* hx   = (const float*)d_in[1];
  const float* cx   = (const float*)d_in[2];
  const float* embw = (const float*)d_in[3];
  const float* Wih0 = (const float*)d_in[4];
  const float* Whh0 = (const float*)d_in[5];
  const float* bih0 = (const float*)d_in[6];
  const float* bhh0 = (const float*)d_in[7];
  const float* Wih1 = (const float*)d_in[8];
  const float* Whh1 = (const float*)d_in[9];
  const float* bih1 = (const float*)d_in[10];
  const float* bhh1 = (const float*)d_in[11];
  const float* Wp   = (const float*)d_in[12];
  const float* bp   = (const float*)d_in[13];
  const float* Wd   = (const float*)d_in[14];
  const float* bd   = (const float*)d_in[15];
  float* out = (float*)d_out;

  char* w = (char*)d_ws;
  bf16* Wih0b = (bf16*)w; w += 4096l*512*2;       // permuted rows
  bf16* Wpb   = (bf16*)w; w += 512l*1024*2;
  bf16* Wdb   = (bf16*)w; w += 50176l*512*2;      // padded to 196*256 rows
  bf16* embb  = (bf16*)w; w += 2048l*512*2;
  float* g0p  = (float*)w; w += 2048l*4096*4;     // [b][t][r][q] layout
  bf16* h0a   = (bf16*)w; w += 2048l*1024*2;
  bf16* h1a   = (bf16*)w; w += 2048l*1024*2;
  bf16* hinit = (bf16*)w; w += 2l*32*1024*2;
  bf16* pb    = (bf16*)w; w += 2048l*512*2;
  unsigned* flags = (unsigned*)w; w += 8192*4;

  k_cvt_perm<<<4096, 128, 0, stream>>>(Wih0, Wih0b);
  k_init<<<256, 256, 0, stream>>>(hx, hinit, flags);
  k_embed<<<2048, 128, 0, stream>>>(ids, embw, embb);

  // layer-0 input-side GEMM for ALL timesteps -> g0p layout; folds bih0+bhh0
  gemm_bt<2><<<dim3(32, 16), 256, 0, stream>>>(
      embb, Wih0b, bih0, bhh0, g0p, nullptr, 2048, 4096, 512, 4096);

  // persistent pipelined recurrence: one dispatch, 65 super-steps.
  // Wd/Wp casts hidden in waves 1-3's post-publish window (cached).
  float* tail = out + 102400000l;
  k_lstm_persist<<<256, 256, 0, stream>>>(hinit, cx, Whh0, Wih1, Whh1, g0p,
                                          bih1, bhh1, Wd, Wp, Wdb, Wpb,
                                          h0a, h1a, tail, flags);

  // predictor: Linear + BN(eval) + tanh -> bf16
  gemm_bt<1><<<dim3(4, 16), 256, 0, stream>>>(
      h1a, Wpb, bp, nullptr, nullptr, pb, 2048, 512, 1024, 512);

  // decoder: [2048,512] @ [50176,512]^T (padded), 256x256 tiles, double-
  // buffered counted-vmcnt staging, non-temporal C stores
  gemm_dec<<<dim3(196, 8), 512, 0, stream>>>(
      pb, Wdb, bd, out, 2048, 50176, 512, 50000);
}